// Round 3
// baseline (1634.044 us; speedup 1.0000x reference)
//
#include <hip/hip_runtime.h>
#include <hip/hip_bf16.h>

#define NEG_BIG (-3.402823466e38f)

__device__ __forceinline__ float bfl(unsigned w) { return __uint_as_float(w << 16); }
__device__ __forceinline__ float bfh(unsigned w) { return __uint_as_float(w & 0xffff0000u); }
__device__ __forceinline__ unsigned f2bf(float f) {
    unsigned u = __float_as_uint(f);
    return (u + 0x7fffu + ((u >> 16) & 1u)) >> 16;  // RNE, finite data
}

// ---------------- CSR build ----------------
__global__ void deg_kernel(const int* __restrict__ dst, int* __restrict__ deg, int E) {
    int e = blockIdx.x * blockDim.x + threadIdx.x;
    if (e < E) atomicAdd(&deg[dst[e]], 1);
}

__global__ void scan_kernel(const int* __restrict__ deg, int* __restrict__ off,
                            int* __restrict__ cursor, int n) {
    __shared__ int sh[1024];
    int tid = threadIdx.x;
    int chunk = (n + 1023) >> 10;
    int s0 = tid * chunk, s1 = min(s0 + chunk, n);
    int sum = 0;
    for (int i = s0; i < s1; ++i) sum += deg[i];
    sh[tid] = sum;
    __syncthreads();
    for (int d = 1; d < 1024; d <<= 1) {
        int t = 0;
        if (tid >= d) t = sh[tid - d];
        __syncthreads();
        sh[tid] += t;
        __syncthreads();
    }
    int run = sh[tid] - sum;  // exclusive prefix
    for (int i = s0; i < s1; ++i) {
        off[i] = run; cursor[i] = run;
        run += deg[i];
    }
    if (tid == 1023) off[n] = sh[1023];
}

__global__ void scatter_kernel(const int* __restrict__ src, const int* __restrict__ dst,
                               int* __restrict__ cursor, int* __restrict__ srcs, int E) {
    int e = blockIdx.x * blockDim.x + threadIdx.x;
    if (e < E) {
        int p = atomicAdd(&cursor[dst[e]], 1);
        srcs[p] = src[e];
    }
}

// ---------------- lin1: x(n,3) -> q f32, k/v bf16-packed, skip f32 (all width 64) ----
// block 256 = 8 nodes x 32 lanes; lane owns channels 2l, 2l+1
__global__ void lin1_kernel(const float* __restrict__ x,
                            const float* __restrict__ Wq, const float* __restrict__ bq,
                            const float* __restrict__ Wk, const float* __restrict__ bk,
                            const float* __restrict__ Wv, const float* __restrict__ bv,
                            const float* __restrict__ Ws, const float* __restrict__ bs,
                            float* __restrict__ q, unsigned* __restrict__ kp,
                            unsigned* __restrict__ vp, float* __restrict__ sk, int n) {
    int i = blockIdx.x * 8 + (threadIdx.x >> 5);
    int hl = threadIdx.x & 31;
    if (i >= n) return;
    float x0 = x[i * 3], x1 = x[i * 3 + 1], x2 = x[i * 3 + 2];
    int c = 2 * hl;
#define DOT2(W, B, O)                                                                  \
    {                                                                                  \
        float2 w0 = *(const float2*)&W[c], w1 = *(const float2*)&W[64 + c],            \
               w2 = *(const float2*)&W[128 + c];                                       \
        float2 bb = *(const float2*)&B[c];                                             \
        O.x = bb.x + x0 * w0.x + x1 * w1.x + x2 * w2.x;                                \
        O.y = bb.y + x0 * w0.y + x1 * w1.y + x2 * w2.y;                                \
    }
    float2 oq, ok, ov, os;
    DOT2(Wq, bq, oq) DOT2(Wk, bk, ok) DOT2(Wv, bv, ov) DOT2(Ws, bs, os)
#undef DOT2
    *(float2*)&q[(size_t)i * 64 + c] = oq;
    *(float2*)&sk[(size_t)i * 64 + c] = os;
    kp[(size_t)i * 32 + hl] = f2bf(ok.x) | (f2bf(ok.y) << 16);
    vp[(size_t)i * 32 + hl] = f2bf(ov.x) | (f2bf(ov.y) << 16);
}

// ---------------- lin2: h1(n,64) -> q f32, k/v bf16-packed, skip f32 (width 128) ----
// block 256 = 4 nodes x 64 lanes; lane owns channels 2l, 2l+1
__global__ void lin2_kernel(const float* __restrict__ h1,
                            const float* __restrict__ Wq, const float* __restrict__ bq,
                            const float* __restrict__ Wk, const float* __restrict__ bk,
                            const float* __restrict__ Wv, const float* __restrict__ bv,
                            const float* __restrict__ Ws, const float* __restrict__ bs,
                            float* __restrict__ q, unsigned* __restrict__ kp,
                            unsigned* __restrict__ vp, float* __restrict__ sk, int n) {
    int i = blockIdx.x * 4 + (threadIdx.x >> 6);
    int lane = threadIdx.x & 63;
    if (i >= n) return;
    int c = 2 * lane;
    float2 aq = *(const float2*)&bq[c];
    float2 ak = *(const float2*)&bk[c];
    float2 av = *(const float2*)&bv[c];
    float2 as_ = *(const float2*)&bs[c];
    for (int kk = 0; kk < 64; ++kk) {
        float hv = h1[(size_t)i * 64 + kk];
        float2 wq = *(const float2*)&Wq[kk * 128 + c];
        float2 wk = *(const float2*)&Wk[kk * 128 + c];
        float2 wv = *(const float2*)&Wv[kk * 128 + c];
        float2 ws = *(const float2*)&Ws[kk * 128 + c];
        aq.x += hv * wq.x; aq.y += hv * wq.y;
        ak.x += hv * wk.x; ak.y += hv * wk.y;
        av.x += hv * wv.x; av.y += hv * wv.y;
        as_.x += hv * ws.x; as_.y += hv * ws.y;
    }
    *(float2*)&q[(size_t)i * 128 + c] = aq;
    *(float2*)&sk[(size_t)i * 128 + c] = as_;
    kp[(size_t)i * 64 + lane] = f2bf(ak.x) | (f2bf(ak.y) << 16);
    vp[(size_t)i * 64 + lane] = f2bf(av.x) | (f2bf(av.y) << 16);
}

// ---------------- attn1: C=64, H=2, d=32. One wave per dst node. ----------------
// Lane (l&31) owns channels 2(l&31), 2(l&31)+1; halves process alternating edges;
// online-softmax states merged across halves at the end. out = relu(attn + skip).
__global__ void attn1_kernel(const float* __restrict__ q, const unsigned* __restrict__ kp,
                             const unsigned* __restrict__ vp, const float* __restrict__ skip,
                             const int* __restrict__ off, const int* __restrict__ srcs,
                             float* __restrict__ out, int n) {
    int i = blockIdx.x * (blockDim.x >> 6) + (threadIdx.x >> 6);
    int lane = threadIdx.x & 63;
    if (i >= n) return;
    int hl = lane & 31, half = lane >> 5;
    int e0 = off[i], e1 = off[i + 1];
    const float scale = 0.17677669529663688f;  // 1/sqrt(32)
    float2 qv = *(const float2*)&q[(size_t)i * 64 + 2 * hl];
    float m = NEG_BIG, den = 0.f, a0 = 0.f, a1 = 0.f;
    for (int e = e0 + half; e < e1; e += 2) {
        int j = srcs[e];
        unsigned kb = kp[(size_t)j * 32 + hl];
        float t = qv.x * bfl(kb) + qv.y * bfh(kb);
        t += __shfl_xor(t, 1);
        t += __shfl_xor(t, 2);
        t += __shfl_xor(t, 4);
        t += __shfl_xor(t, 8);
        float s = t * scale;
        float mn = fmaxf(m, s);
        float corr = __expf(m - mn);
        float p = __expf(s - mn);
        unsigned vb = vp[(size_t)j * 32 + hl];
        den = den * corr + p;
        a0 = a0 * corr + p * bfl(vb);
        a1 = a1 * corr + p * bfh(vb);
        m = mn;
    }
    // merge the two halves' online-softmax states
    float mo = __shfl_xor(m, 32);
    float dno = __shfl_xor(den, 32);
    float a0o = __shfl_xor(a0, 32);
    float a1o = __shfl_xor(a1, 32);
    float mm = fmaxf(m, mo);
    float c0 = __expf(m - mm), c1 = __expf(mo - mm);
    den = den * c0 + dno * c1;
    a0 = a0 * c0 + a0o * c1;
    a1 = a1 * c0 + a1o * c1;
    if (half == 0) {
        float inv = 1.f / fmaxf(den, 1e-16f);
        float2 sk = *(const float2*)&skip[(size_t)i * 64 + 2 * hl];
        float2 o;
        o.x = fmaxf(a0 * inv + sk.x, 0.f);
        o.y = fmaxf(a1 * inv + sk.y, 0.f);
        *(float2*)&out[(size_t)i * 64 + 2 * hl] = o;
    }
}

// ---------------- attn2: C=128, H=2, d=64. One wave per dst node. ----------------
// Lane (l&31) owns channels 4(l&31)..+3 in the loop; halves alternate edges; merged,
// remapped to 2-channel layout, skip+relu applied, then pooled via atomicMax.
__global__ void attn2_kernel(const float* __restrict__ q, const unsigned* __restrict__ kp,
                             const unsigned* __restrict__ vp, const float* __restrict__ skip,
                             const int* __restrict__ off, const int* __restrict__ srcs,
                             const int* __restrict__ batch, unsigned* __restrict__ pool,
                             int n) {
    int i = blockIdx.x * (blockDim.x >> 6) + (threadIdx.x >> 6);
    int lane = threadIdx.x & 63;
    if (i >= n) return;
    int hl = lane & 31, half = lane >> 5;
    int e0 = off[i], e1 = off[i + 1];
    const float scale = 0.125f;  // 1/sqrt(64)
    float4 qv = *(const float4*)&q[(size_t)i * 128 + 4 * hl];
    float m = NEG_BIG, den = 0.f;
    float ax = 0.f, ay = 0.f, az = 0.f, aw = 0.f;
    for (int e = e0 + half; e < e1; e += 2) {
        int j = srcs[e];
        uint2 kb = *(const uint2*)&kp[(size_t)j * 64 + 2 * hl];
        float t = qv.x * bfl(kb.x) + qv.y * bfh(kb.x) + qv.z * bfl(kb.y) + qv.w * bfh(kb.y);
        t += __shfl_xor(t, 1);
        t += __shfl_xor(t, 2);
        t += __shfl_xor(t, 4);
        t += __shfl_xor(t, 8);
        float s = t * scale;
        float mn = fmaxf(m, s);
        float corr = __expf(m - mn);
        float p = __expf(s - mn);
        uint2 vb = *(const uint2*)&vp[(size_t)j * 64 + 2 * hl];
        den = den * corr + p;
        ax = ax * corr + p * bfl(vb.x);
        ay = ay * corr + p * bfh(vb.x);
        az = az * corr + p * bfl(vb.y);
        aw = aw * corr + p * bfh(vb.y);
        m = mn;
    }
    // merge halves (lanes l and l+32 own the same channels)
    float mo = __shfl_xor(m, 32);
    float mm = fmaxf(m, mo);
    float c0 = __expf(m - mm), c1 = __expf(mo - mm);
    den = den * c0 + __shfl_xor(den, 32) * c1;
    ax = ax * c0 + __shfl_xor(ax, 32) * c1;
    ay = ay * c0 + __shfl_xor(ay, 32) * c1;
    az = az * c0 + __shfl_xor(az, 32) * c1;
    aw = aw * c0 + __shfl_xor(aw, 32) * c1;
    float inv = 1.f / fmaxf(den, 1e-16f);
    float o0 = ax * inv, o1 = ay * inv, o2 = az * inv, o3 = aw * inv;
    // remap: lane l wants channels 2l, 2l+1 which live on source lane g = l>>1
    int g = lane >> 1;
    float b0 = __shfl(o0, g), b1 = __shfl(o1, g), b2 = __shfl(o2, g), b3 = __shfl(o3, g);
    float v0 = (lane & 1) ? b2 : b0;
    float v1 = (lane & 1) ? b3 : b1;
    float2 sk = *(const float2*)&skip[(size_t)i * 128 + 2 * lane];
    v0 = fmaxf(v0 + sk.x, 0.f);
    v1 = fmaxf(v1 + sk.y, 0.f);
    int gg = batch[i];
    unsigned* pb = &pool[(size_t)gg * 128 + 2 * lane];
    atomicMax(pb, __float_as_uint(v0));
    atomicMax(pb + 1, __float_as_uint(v1));
}

// ---------------- MLP head ----------------
__global__ void head_kernel(const unsigned* __restrict__ pbits,
                            const float* __restrict__ W1, const float* __restrict__ b1,
                            const float* __restrict__ W2, const float* __restrict__ b2,
                            const float* __restrict__ W3, const float* __restrict__ b3,
                            float* __restrict__ out, int G) {
    int g = blockIdx.x;
    int t = threadIdx.x;  // 128 threads
    __shared__ float ps[128], xl[32], y[128];
    ps[t] = __uint_as_float(pbits[g * 128 + t]);
    __syncthreads();
    if (t < 32) {
        float a = b1[t];
        for (int k = 0; k < 128; ++k) a += ps[k] * W1[k * 32 + t];
        a = fmaxf(a, 0.f);
        xl[t] = a;
        out[G * 40 + g * 32 + t] = a;  // x_latent block after out0 block
    }
    __syncthreads();
    {
        float a = b2[t];
        for (int k = 0; k < 32; ++k) a += xl[k] * W2[k * 128 + t];
        y[t] = fmaxf(a, 0.f);
    }
    __syncthreads();
    if (t < 40) {
        float a = b3[t];
        for (int k = 0; k < 128; ++k) a += y[k] * W3[k * 40 + t];  // W3 is (128,40)
        out[g * 40 + t] = a;
    }
}

extern "C" void kernel_launch(void* const* d_in, const int* in_sizes, int n_in,
                              void* d_out, int out_size, void* d_ws, size_t ws_size,
                              hipStream_t stream) {
    const float* x = (const float*)d_in[0];
    const int* eidx = (const int*)d_in[1];
    const int* batch = (const int*)d_in[2];
    const float *Wq1 = (const float*)d_in[3], *bq1 = (const float*)d_in[4];
    const float *Wk1 = (const float*)d_in[5], *bk1 = (const float*)d_in[6];
    const float *Wv1 = (const float*)d_in[7], *bv1 = (const float*)d_in[8];
    const float *Ws1 = (const float*)d_in[9], *bs1 = (const float*)d_in[10];
    const float *Wq2 = (const float*)d_in[11], *bq2 = (const float*)d_in[12];
    const float *Wk2 = (const float*)d_in[13], *bk2 = (const float*)d_in[14];
    const float *Wv2 = (const float*)d_in[15], *bv2 = (const float*)d_in[16];
    const float *Ws2 = (const float*)d_in[17], *bs2 = (const float*)d_in[18];
    const float *W1 = (const float*)d_in[19], *b1 = (const float*)d_in[20];
    const float *W2 = (const float*)d_in[21], *b2 = (const float*)d_in[22];
    const float *W3 = (const float*)d_in[23], *b3 = (const float*)d_in[24];

    const int N = in_sizes[0] / 3;
    const int E = in_sizes[1] / 2;
    const int G = out_size / 72;  // 40 + 32 per graph
    const int* esrc = eidx;
    const int* edst = eidx + E;

    // workspace carve-out; layer-2 buffers overlay layer-1 buffers (dead by then)
    char* w = (char*)d_ws;
    size_t o = 0;
    auto alloc = [&](size_t bytes) {
        void* p = w + o;
        o = (o + bytes + 255) & ~(size_t)255;
        return p;
    };
    char* uni = (char*)alloc((size_t)N * 128 * 4 + (size_t)N * 64 * 4 * 2 +
                             (size_t)N * 128 * 4);  // 76.8 MB union region
    float* h1 = (float*)alloc((size_t)N * 64 * 4);
    int* deg = (int*)alloc((size_t)N * 4);
    int* off = (int*)alloc((size_t)(N + 1) * 4);
    int* cursor = (int*)alloc((size_t)N * 4);
    int* srcs = (int*)alloc((size_t)E * 4);
    unsigned* pool = (unsigned*)alloc((size_t)G * 128 * 4);
    (void)ws_size;

    // layer-1 views into union region
    float* q1 = (float*)uni;                            // N*64 f32
    unsigned* kp1 = (unsigned*)(uni + (size_t)N * 256); // N*32 u32
    unsigned* vp1 = kp1 + (size_t)N * 32;               // N*32 u32
    float* s1 = (float*)(vp1 + (size_t)N * 32);         // N*64 f32
    // layer-2 views (overlay)
    float* q2 = (float*)uni;                            // N*128 f32
    unsigned* kp2 = (unsigned*)(uni + (size_t)N * 512); // N*64 u32
    unsigned* vp2 = kp2 + (size_t)N * 64;               // N*64 u32
    float* s2 = (float*)(vp2 + (size_t)N * 64);         // N*128 f32

    // CSR by destination
    hipMemsetAsync(deg, 0, (size_t)N * 4, stream);
    deg_kernel<<<(E + 255) / 256, 256, 0, stream>>>(edst, deg, E);
    scan_kernel<<<1, 1024, 0, stream>>>(deg, off, cursor, N);
    scatter_kernel<<<(E + 255) / 256, 256, 0, stream>>>(esrc, edst, cursor, srcs, E);

    // layer 1
    lin1_kernel<<<(N + 7) / 8, 256, 0, stream>>>(x, Wq1, bq1, Wk1, bk1, Wv1, bv1, Ws1, bs1,
                                                 q1, kp1, vp1, s1, N);
    attn1_kernel<<<(N + 3) / 4, 256, 0, stream>>>(q1, kp1, vp1, s1, off, srcs, h1, N);

    // layer 2 (+ fused max-pool)
    lin2_kernel<<<(N + 3) / 4, 256, 0, stream>>>(h1, Wq2, bq2, Wk2, bk2, Wv2, bv2, Ws2, bs2,
                                                 q2, kp2, vp2, s2, N);
    hipMemsetAsync(pool, 0, (size_t)G * 128 * 4, stream);
    attn2_kernel<<<(N + 3) / 4, 256, 0, stream>>>(q2, kp2, vp2, s2, off, srcs, batch, pool, N);

    // head
    head_kernel<<<G, 128, 0, stream>>>(pool, W1, b1, W2, b2, W3, b3, (float*)d_out, G);
}

// Round 5
// 523.841 us; speedup vs baseline: 3.1193x; 3.1193x over previous
//
#include <hip/hip_runtime.h>
#include <hip/hip_bf16.h>

#define NEG_BIG (-3.402823466e38f)

typedef short s16x8 __attribute__((ext_vector_type(8)));   // 8 bf16 (4 VGPRs)
typedef float f32x4 __attribute__((ext_vector_type(4)));

__device__ __forceinline__ float bfl(unsigned w) { return __uint_as_float(w << 16); }
__device__ __forceinline__ float bfh(unsigned w) { return __uint_as_float(w & 0xffff0000u); }
__device__ __forceinline__ unsigned f2bf(float f) {
    unsigned u = __float_as_uint(f);
    return (u + 0x7fffu + ((u >> 16) & 1u)) >> 16;  // RNE, finite data
}

// ---------------- CSR build ----------------
__global__ void deg_kernel(const int* __restrict__ dst, int* __restrict__ deg, int E) {
    int e = blockIdx.x * blockDim.x + threadIdx.x;
    if (e < E) atomicAdd(&deg[dst[e]], 1);
}

__global__ void scan_kernel(const int* __restrict__ deg, int* __restrict__ off,
                            int* __restrict__ cursor, int n) {
    __shared__ int sh[1024];
    int tid = threadIdx.x;
    int chunk = (n + 1023) >> 10;
    int s0 = tid * chunk, s1 = min(s0 + chunk, n);
    int sum = 0;
    for (int i = s0; i < s1; ++i) sum += deg[i];
    sh[tid] = sum;
    __syncthreads();
    for (int d = 1; d < 1024; d <<= 1) {
        int t = 0;
        if (tid >= d) t = sh[tid - d];
        __syncthreads();
        sh[tid] += t;
        __syncthreads();
    }
    int run = sh[tid] - sum;  // exclusive prefix
    for (int i = s0; i < s1; ++i) {
        off[i] = run; cursor[i] = run;
        run += deg[i];
    }
    if (tid == 1023) off[n] = sh[1023];
}

__global__ void scatter_kernel(const int* __restrict__ src, const int* __restrict__ dst,
                               int* __restrict__ cursor, int* __restrict__ srcs, int E) {
    int e = blockIdx.x * blockDim.x + threadIdx.x;
    if (e < E) {
        int p = atomicAdd(&cursor[dst[e]], 1);
        srcs[p] = src[e];
    }
}

// ---------------- lin1: x(n,3) -> q f32, k/v bf16-packed, skip f32 ----------------
// block 256 = 8 nodes x 32 lanes; lane owns channels 2l, 2l+1 (weights L1-hot)
__global__ void lin1_kernel(const float* __restrict__ x,
                            const float* __restrict__ Wq, const float* __restrict__ bq,
                            const float* __restrict__ Wk, const float* __restrict__ bk,
                            const float* __restrict__ Wv, const float* __restrict__ bv,
                            const float* __restrict__ Ws, const float* __restrict__ bs,
                            float* __restrict__ q, unsigned* __restrict__ kp,
                            unsigned* __restrict__ vp, float* __restrict__ sk, int n) {
    int i = blockIdx.x * 8 + (threadIdx.x >> 5);
    int hl = threadIdx.x & 31;
    if (i >= n) return;
    float x0 = x[i * 3], x1 = x[i * 3 + 1], x2 = x[i * 3 + 2];
    int c = 2 * hl;
#define DOT2(W, B, O)                                                                  \
    {                                                                                  \
        float2 w0 = *(const float2*)&W[c], w1 = *(const float2*)&W[64 + c],            \
               w2 = *(const float2*)&W[128 + c];                                       \
        float2 bb = *(const float2*)&B[c];                                             \
        O.x = bb.x + x0 * w0.x + x1 * w1.x + x2 * w2.x;                                \
        O.y = bb.y + x0 * w0.y + x1 * w1.y + x2 * w2.y;                                \
    }
    float2 oq, ok, ov, os;
    DOT2(Wq, bq, oq) DOT2(Wk, bk, ok) DOT2(Wv, bv, ov) DOT2(Ws, bs, os)
#undef DOT2
    *(float2*)&q[(size_t)i * 64 + c] = oq;
    *(float2*)&sk[(size_t)i * 64 + c] = os;
    kp[(size_t)i * 32 + hl] = f2bf(ok.x) | (f2bf(ok.y) << 16);
    vp[(size_t)i * 32 + hl] = f2bf(ov.x) | (f2bf(ov.y) << 16);
}

// ---------------- attn1: C=64, H=2, d=32 (half-split: 2 edges in flight) ----------
// Output h1 written directly as packed bf16 (feeds the MFMA lin2).
__global__ void attn1_kernel(const float* __restrict__ q, const unsigned* __restrict__ kp,
                             const unsigned* __restrict__ vp, const float* __restrict__ skip,
                             const int* __restrict__ off, const int* __restrict__ srcs,
                             unsigned* __restrict__ h1b, int n) {
    int i = blockIdx.x * (blockDim.x >> 6) + (threadIdx.x >> 6);
    int lane = threadIdx.x & 63;
    if (i >= n) return;
    int hl = lane & 31, half = lane >> 5;
    int e0 = off[i], e1 = off[i + 1];
    const float scale = 0.17677669529663688f;  // 1/sqrt(32)
    float2 qv = *(const float2*)&q[(size_t)i * 64 + 2 * hl];
    float m = NEG_BIG, den = 0.f, a0 = 0.f, a1 = 0.f;
    for (int e = e0 + half; e < e1; e += 2) {
        int j = srcs[e];
        unsigned kb = kp[(size_t)j * 32 + hl];
        float t = qv.x * bfl(kb) + qv.y * bfh(kb);
        t += __shfl_xor(t, 1);
        t += __shfl_xor(t, 2);
        t += __shfl_xor(t, 4);
        t += __shfl_xor(t, 8);
        float s = t * scale;
        float mn = fmaxf(m, s);
        float corr = __expf(m - mn);
        float p = __expf(s - mn);
        unsigned vb = vp[(size_t)j * 32 + hl];
        den = den * corr + p;
        a0 = a0 * corr + p * bfl(vb);
        a1 = a1 * corr + p * bfh(vb);
        m = mn;
    }
    // merge the two halves' online-softmax states
    float mo = __shfl_xor(m, 32);
    float dno = __shfl_xor(den, 32);
    float a0o = __shfl_xor(a0, 32);
    float a1o = __shfl_xor(a1, 32);
    float mm = fmaxf(m, mo);
    float c0 = __expf(m - mm), c1 = __expf(mo - mm);
    den = den * c0 + dno * c1;
    a0 = a0 * c0 + a0o * c1;
    a1 = a1 * c0 + a1o * c1;
    if (half == 0) {
        float inv = 1.f / fmaxf(den, 1e-16f);
        float2 sk = *(const float2*)&skip[(size_t)i * 64 + 2 * hl];
        float o0 = fmaxf(a0 * inv + sk.x, 0.f);
        float o1 = fmaxf(a1 * inv + sk.y, 0.f);
        h1b[(size_t)i * 32 + hl] = f2bf(o0) | (f2bf(o1) << 16);
    }
}

// ---------------- prep: pack [Wq2|Wk2|Wv2|Ws2] (64x128 f32 each) into MFMA B-frags --
// frag = ct*2+ks (ct=col-tile of 16, ks=K-step of 32); lane l holds col (l&15),
// k = ks*32 + (l>>4)*8 + [0..8) -> 8 contiguous ushorts at bfrag[frag*512 + l*8].
__global__ void prep_w2(const float* __restrict__ Wq, const float* __restrict__ Wk,
                        const float* __restrict__ Wv, const float* __restrict__ Ws,
                        ushort* __restrict__ bfrag) {
    int t = blockIdx.x * blockDim.x + threadIdx.x;  // 4096 threads
    int frag = t >> 6, l = t & 63;
    int ct = frag >> 1, ks = frag & 1;
    int m = ct >> 3;
    const float* W = (m == 0) ? Wq : (m == 1) ? Wk : (m == 2) ? Wv : Ws;
    int c = (ct & 7) * 16 + (l & 15);
    int kbase = ks * 32 + ((l >> 4) << 3);
#pragma unroll
    for (int e = 0; e < 8; ++e)
        bfrag[(size_t)frag * 512 + l * 8 + e] = (ushort)f2bf(W[(kbase + e) * 128 + c]);
}

// ---------------- lin2 as MFMA GEMM: h1b(n,64 bf16) @ [Wq|Wk|Wv|Ws](64,512 bf16) ----
// Block = 16 nodes x 512 cols, 4 waves; wave w owns matrix w (uniform epilogue).
__global__ __launch_bounds__(256) void lin2m_kernel(
        const ushort* __restrict__ h1b, const ushort* __restrict__ bfrag,
        const float* __restrict__ bq, const float* __restrict__ bk,
        const float* __restrict__ bv, const float* __restrict__ bs,
        float* __restrict__ q2, ushort* __restrict__ k2b, ushort* __restrict__ v2b,
        float* __restrict__ s2, int n) {
    int node0 = blockIdx.x * 16;
    int w = threadIdx.x >> 6, l = threadIdx.x & 63;
    int arow = node0 + (l & 15);
    if (arow >= n) arow = n - 1;
    s16x8 a0 = *(const s16x8*)&h1b[(size_t)arow * 64 + ((l >> 4) << 3)];
    s16x8 a1 = *(const s16x8*)&h1b[(size_t)arow * 64 + 32 + ((l >> 4) << 3)];
    const float* bias = (w == 0) ? bq : (w == 1) ? bk : (w == 2) ? bv : bs;
    int cl = l & 15;
#pragma unroll
    for (int ctl = 0; ctl < 8; ++ctl) {
        int ct = w * 8 + ctl;
        s16x8 b0 = *(const s16x8*)&bfrag[(size_t)(ct * 2 + 0) * 512 + l * 8];
        s16x8 b1 = *(const s16x8*)&bfrag[(size_t)(ct * 2 + 1) * 512 + l * 8];
        f32x4 acc = {0.f, 0.f, 0.f, 0.f};
        acc = __builtin_amdgcn_mfma_f32_16x16x32_bf16(a0, b0, acc, 0, 0, 0);
        acc = __builtin_amdgcn_mfma_f32_16x16x32_bf16(a1, b1, acc, 0, 0, 0);
        int cg = ctl * 16 + cl;
        float bb = bias[cg];
#pragma unroll
        for (int r = 0; r < 4; ++r) {
            int node = node0 + ((l >> 4) << 2) + r;
            if (node < n) {
                float val = acc[r] + bb;
                if (w == 0) q2[(size_t)node * 128 + cg] = val;
                else if (w == 1) k2b[(size_t)node * 128 + cg] = (ushort)f2bf(val);
                else if (w == 2) v2b[(size_t)node * 128 + cg] = (ushort)f2bf(val);
                else s2[(size_t)node * 128 + cg] = val;
            }
        }
    }
}

// ---------------- attn2: C=128, H=2, d=64. Full wave, one edge/iter. --------------
// Lane l owns channels 2l, 2l+1; head = l>>5; 5-shuffle reduce within 32-lane half.
// Fused skip + relu + atomicMax pooling.
__global__ void attn2_kernel(const float* __restrict__ q, const unsigned* __restrict__ k2u,
                             const unsigned* __restrict__ v2u, const float* __restrict__ skip,
                             const int* __restrict__ off, const int* __restrict__ srcs,
                             const int* __restrict__ batch, unsigned* __restrict__ pool,
                             int n) {
    int i = blockIdx.x * (blockDim.x >> 6) + (threadIdx.x >> 6);
    int lane = threadIdx.x & 63;
    if (i >= n) return;
    int e0 = off[i], e1 = off[i + 1];
    const float scale = 0.125f;  // 1/sqrt(64)
    float2 qv = *(const float2*)&q[(size_t)i * 128 + 2 * lane];
    float m = NEG_BIG, den = 0.f, ax = 0.f, ay = 0.f;
    for (int e = e0; e < e1; ++e) {
        int j = srcs[e];
        unsigned kb = k2u[(size_t)j * 64 + lane];
        float t = qv.x * bfl(kb) + qv.y * bfh(kb);
        t += __shfl_xor(t, 1);
        t += __shfl_xor(t, 2);
        t += __shfl_xor(t, 4);
        t += __shfl_xor(t, 8);
        t += __shfl_xor(t, 16);
        float s = t * scale;
        float mn = fmaxf(m, s);
        float corr = __expf(m - mn);
        float p = __expf(s - mn);
        unsigned vb = v2u[(size_t)j * 64 + lane];
        den = den * corr + p;
        ax = ax * corr + p * bfl(vb);
        ay = ay * corr + p * bfh(vb);
        m = mn;
    }
    float inv = 1.f / fmaxf(den, 1e-16f);
    float2 sk = *(const float2*)&skip[(size_t)i * 128 + 2 * lane];
    float v0 = fmaxf(ax * inv + sk.x, 0.f);
    float v1 = fmaxf(ay * inv + sk.y, 0.f);
    int g = batch[i];
    unsigned* pb = &pool[(size_t)g * 128 + 2 * lane];
    atomicMax(pb, __float_as_uint(v0));
    atomicMax(pb + 1, __float_as_uint(v1));
}

// ---------------- MLP head ----------------
__global__ void head_kernel(const unsigned* __restrict__ pbits,
                            const float* __restrict__ W1, const float* __restrict__ b1,
                            const float* __restrict__ W2, const float* __restrict__ b2,
                            const float* __restrict__ W3, const float* __restrict__ b3,
                            float* __restrict__ out, int G) {
    int g = blockIdx.x;
    int t = threadIdx.x;  // 128 threads
    __shared__ float ps[128], xl[32], y[128];
    ps[t] = __uint_as_float(pbits[g * 128 + t]);
    __syncthreads();
    if (t < 32) {
        float a = b1[t];
        for (int k = 0; k < 128; ++k) a += ps[k] * W1[k * 32 + t];
        a = fmaxf(a, 0.f);
        xl[t] = a;
        out[G * 40 + g * 32 + t] = a;  // x_latent block after out0 block
    }
    __syncthreads();
    {
        float a = b2[t];
        for (int k = 0; k < 32; ++k) a += xl[k] * W2[k * 128 + t];
        y[t] = fmaxf(a, 0.f);
    }
    __syncthreads();
    if (t < 40) {
        float a = b3[t];
        for (int k = 0; k < 128; ++k) a += y[k] * W3[k * 40 + t];  // W3 is (128,40)
        out[g * 40 + t] = a;
    }
}

extern "C" void kernel_launch(void* const* d_in, const int* in_sizes, int n_in,
                              void* d_out, int out_size, void* d_ws, size_t ws_size,
                              hipStream_t stream) {
    const float* x = (const float*)d_in[0];
    const int* eidx = (const int*)d_in[1];
    const int* batch = (const int*)d_in[2];
    const float *Wq1 = (const float*)d_in[3], *bq1 = (const float*)d_in[4];
    const float *Wk1 = (const float*)d_in[5], *bk1 = (const float*)d_in[6];
    const float *Wv1 = (const float*)d_in[7], *bv1 = (const float*)d_in[8];
    const float *Ws1 = (const float*)d_in[9], *bs1 = (const float*)d_in[10];
    const float *Wq2 = (const float*)d_in[11], *bq2 = (const float*)d_in[12];
    const float *Wk2 = (const float*)d_in[13], *bk2 = (const float*)d_in[14];
    const float *Wv2 = (const float*)d_in[15], *bv2 = (const float*)d_in[16];
    const float *Ws2 = (const float*)d_in[17], *bs2 = (const float*)d_in[18];
    const float *W1 = (const float*)d_in[19], *b1 = (const float*)d_in[20];
    const float *W2 = (const float*)d_in[21], *b2 = (const float*)d_in[22];
    const float *W3 = (const float*)d_in[23], *b3 = (const float*)d_in[24];

    const int N = in_sizes[0] / 3;
    const int E = in_sizes[1] / 2;
    const int G = out_size / 72;  // 40 + 32 per graph
    const int* esrc = eidx;
    const int* edst = eidx + E;

    // workspace carve-out; layer-2 buffers overlay layer-1 buffers (dead by then).
    // Union region must hold the LAYER-2 view, which is the larger:
    //   q2 (N*512B) + k2b (N*256B) + v2b (N*256B) + s2 (N*512B) = N*1536 bytes.
    // (Round-4 bug: sized it N*1280 -> s2 spilled into h1b/bfrag/srcs -> GPU fault.)
    char* w = (char*)d_ws;
    size_t o = 0;
    auto alloc = [&](size_t bytes) {
        void* p = w + o;
        o = (o + bytes + 255) & ~(size_t)255;
        return p;
    };
    char* uni = (char*)alloc((size_t)N * 1536);            // 76.8MB union region
    unsigned* h1b = (unsigned*)alloc((size_t)N * 32 * 4);  // bf16 h1, packed (6.4MB)
    ushort* bfrag = (ushort*)alloc(64 * 512 * 2);          // 64KB packed W2 B-frags
    int* deg = (int*)alloc((size_t)N * 4);
    int* off = (int*)alloc((size_t)(N + 1) * 4);
    int* cursor = (int*)alloc((size_t)N * 4);
    int* srcs = (int*)alloc((size_t)E * 4);
    unsigned* pool = (unsigned*)alloc((size_t)G * 128 * 4);
    (void)ws_size;

    // layer-1 views into union region (uses N*768 bytes)
    float* q1 = (float*)uni;                             // N*64 f32
    unsigned* kp1 = (unsigned*)(uni + (size_t)N * 256);  // N*32 u32
    unsigned* vp1 = kp1 + (size_t)N * 32;                // N*32 u32
    float* s1 = (float*)(vp1 + (size_t)N * 32);          // N*64 f32
    // layer-2 views (overlay, uses N*1536 bytes)
    float* q2 = (float*)uni;                             // N*128 f32
    ushort* k2b = (ushort*)(uni + (size_t)N * 512);      // N*128 bf16
    ushort* v2b = k2b + (size_t)N * 128;                 // N*128 bf16
    float* s2 = (float*)(v2b + (size_t)N * 128);         // N*128 f32

    // CSR by destination
    hipMemsetAsync(deg, 0, (size_t)N * 4, stream);
    deg_kernel<<<(E + 255) / 256, 256, 0, stream>>>(edst, deg, E);
    scan_kernel<<<1, 1024, 0, stream>>>(deg, off, cursor, N);
    scatter_kernel<<<(E + 255) / 256, 256, 0, stream>>>(esrc, edst, cursor, srcs, E);

    // layer 1
    lin1_kernel<<<(N + 7) / 8, 256, 0, stream>>>(x, Wq1, bq1, Wk1, bk1, Wv1, bv1, Ws1, bs1,
                                                 q1, kp1, vp1, s1, N);
    attn1_kernel<<<(N + 3) / 4, 256, 0, stream>>>(q1, kp1, vp1, s1, off, srcs, h1b, N);

    // layer 2 (MFMA linear + fused max-pool attention)
    prep_w2<<<16, 256, 0, stream>>>(Wq2, Wk2, Wv2, Ws2, bfrag);
    lin2m_kernel<<<(N + 15) / 16, 256, 0, stream>>>((const ushort*)h1b, bfrag, bq2, bk2, bv2,
                                                    bs2, q2, k2b, v2b, s2, N);
    hipMemsetAsync(pool, 0, (size_t)G * 128 * 4, stream);
    attn2_kernel<<<(N + 3) / 4, 256, 0, stream>>>(q2, (const unsigned*)k2b,
                                                  (const unsigned*)v2b, s2, off, srcs, batch,
                                                  pool, N);

    // head
    head_kernel<<<G, 128, 0, stream>>>(pool, W1, b1, W2, b2, W3, b3, (float*)d_out, G);
}